// Round 1
// baseline (685.003 us; speedup 1.0000x reference)
//
#include <hip/hip_runtime.h>
#include <math.h>

#define N_COLS 2048
#define NTHREADS 256
#define ELEMS_PER_THREAD (N_COLS / NTHREADS)  // 8

typedef unsigned long long u64;
typedef unsigned int u32;

__global__ void init_acc(double* acc) { *acc = 0.0; }

__global__ void finalize(const double* __restrict__ acc, float* __restrict__ out, int brows) {
    out[0] = (float)(*acc / (double)brows);
}

__global__ __launch_bounds__(NTHREADS)
void listmle_kernel(const float* __restrict__ scores,
                    const float* __restrict__ relevance,
                    const float* __restrict__ mask,
                    double* __restrict__ acc) {
    __shared__ u64 buf[N_COLS];      // 16 KB: sort keys; reused as scan buffer after extraction
    __shared__ float ea[N_COLS];     // 8 KB: exp values / scan ping-pong
    __shared__ float red[NTHREADS / 64];

    const int row = blockIdx.x;
    const int tid = threadIdx.x;
    const size_t base = (size_t)row * N_COLS;

    // ---- load (float4-coalesced) + build 64-bit sort keys ----
    // key = (~rel_bits)<<32 | score_bits : ascending u64 sort == descending relevance.
    for (int k = tid; k < N_COLS / 4; k += NTHREADS) {
        float4 r4 = ((const float4*)(relevance + base))[k];
        float4 s4 = ((const float4*)(scores + base))[k];
        float4 m4 = ((const float4*)(mask + base))[k];
        float rv[4] = {r4.x, r4.y, r4.z, r4.w};
        float sv[4] = {s4.x, s4.y, s4.z, s4.w};
        float mv[4] = {m4.x, m4.y, m4.z, m4.w};
        #pragma unroll
        for (int j = 0; j < 4; ++j) {
            u32 rb = __float_as_uint(rv[j]);
            float s = (mv[j] == 0.0f) ? -INFINITY : sv[j];
            u32 sb = __float_as_uint(s);
            buf[k * 4 + j] = ((u64)(~rb) << 32) | (u64)sb;
        }
    }
    __syncthreads();

    // ---- bitonic sort ascending on u64 ----
    for (int size = 2; size <= N_COLS; size <<= 1) {
        for (int stride = size >> 1; stride > 0; stride >>= 1) {
            #pragma unroll
            for (int e = 0; e < (N_COLS / 2) / NTHREADS; ++e) {
                int t = tid + e * NTHREADS;
                int i = ((t & ~(stride - 1)) << 1) | (t & (stride - 1));
                int j = i | stride;
                bool up = ((i & size) == 0);
                u64 a = buf[i];
                u64 b = buf[j];
                if ((a > b) == up) { buf[i] = b; buf[j] = a; }
            }
            __syncthreads();
        }
    }

    // ---- extract scores (register-resident), row max ----
    float sv[ELEMS_PER_THREAD];
    float lmax = -INFINITY;
    #pragma unroll
    for (int k = 0; k < ELEMS_PER_THREAD; ++k) {
        int i = tid + k * NTHREADS;
        sv[k] = __uint_as_float((u32)(buf[i] & 0xFFFFFFFFull));
        lmax = fmaxf(lmax, sv[k]);
    }
    #pragma unroll
    for (int off = 32; off > 0; off >>= 1)
        lmax = fmaxf(lmax, __shfl_down(lmax, off, 64));
    const int wave = tid >> 6;
    if ((tid & 63) == 0) red[wave] = lmax;
    __syncthreads();
    const float M = fmaxf(fmaxf(red[0], red[1]), fmaxf(red[2], red[3]));
    __syncthreads();

    // ---- e[i] = exp(s[i]-M) ----
    #pragma unroll
    for (int k = 0; k < ELEMS_PER_THREAD; ++k) {
        int i = tid + k * NTHREADS;
        ea[i] = __expf(sv[k] - M);  // exp(-inf - M) = 0 for masked: correct LSE exclusion
    }
    __syncthreads();

    // ---- reverse inclusive scan (suffix sums), Hillis-Steele ping-pong ----
    float* a = ea;
    float* b = (float*)buf;  // buf's keys no longer needed (scores live in sv[])
    for (int d = 1; d < N_COLS; d <<= 1) {
        #pragma unroll
        for (int e = 0; e < ELEMS_PER_THREAD; ++e) {
            int i = tid + e * NTHREADS;
            float v = a[i];
            if (i + d < N_COLS) v += a[i + d];
            b[i] = v;
        }
        __syncthreads();
        float* tmp = a; a = b; b = tmp;
    }
    // `a` holds suffix sums: suff[i] = sum_{j>=i} e[j]

    // ---- loss terms: sum_{i=0}^{N-2} (M + log(suff[i]) - s[i]) ----
    float lsum = 0.0f;
    #pragma unroll
    for (int k = 0; k < ELEMS_PER_THREAD; ++k) {
        int i = tid + k * NTHREADS;
        if (i < N_COLS - 1 && !isinf(sv[k])) {
            lsum += M + __logf(a[i]) - sv[k];
        }
    }
    #pragma unroll
    for (int off = 32; off > 0; off >>= 1)
        lsum += __shfl_down(lsum, off, 64);
    __syncthreads();
    if ((tid & 63) == 0) red[wave] = lsum;
    __syncthreads();
    if (tid == 0) {
        float blocksum = red[0] + red[1] + red[2] + red[3];
        atomicAdd(acc, (double)blocksum);
    }
}

extern "C" void kernel_launch(void* const* d_in, const int* in_sizes, int n_in,
                              void* d_out, int out_size, void* d_ws, size_t ws_size,
                              hipStream_t stream) {
    const float* scores    = (const float*)d_in[0];
    const float* relevance = (const float*)d_in[1];
    const float* mask      = (const float*)d_in[2];
    float* out = (float*)d_out;
    double* acc = (double*)d_ws;
    const int brows = in_sizes[0] / N_COLS;

    init_acc<<<1, 1, 0, stream>>>(acc);
    listmle_kernel<<<brows, NTHREADS, 0, stream>>>(scores, relevance, mask, acc);
    finalize<<<1, 1, 0, stream>>>(acc, out, brows);
}

// Round 2
// 244.299 us; speedup vs baseline: 2.8040x; 2.8040x over previous
//
#include <hip/hip_runtime.h>
#include <math.h>

#define N_COLS 2048
#define NB 2048              // buckets (== N_COLS; uniform relevance -> ~Poisson(1) occupancy)
#define NTHREADS 256
#define EPT 8                // elements per thread

typedef unsigned int u32;

__global__ void init_acc(double* acc) { *acc = 0.0; }

__global__ void finalize(const double* __restrict__ acc, float* __restrict__ out, int brows) {
    out[0] = (float)(*acc / (double)brows);
}

// In-place exclusive scan of 2048 u32: per-thread serial-8 + wave shuffle scan + block combine.
// Call with all 256 threads; array must be stable (sync'd) on entry. Ends with __syncthreads.
__device__ __forceinline__ void scan2048_u32_inplace(u32* arr, u32* wtmp) {
    const int tid = threadIdx.x, lane = tid & 63, wave = tid >> 6;
    u32 v[8];
    u32 run = 0;
    #pragma unroll
    for (int k = 0; k < 8; ++k) { v[k] = arr[tid * 8 + k]; run += v[k]; }
    u32 inc = run;
    #pragma unroll
    for (int off = 1; off < 64; off <<= 1) {
        u32 o = __shfl_up(inc, off, 64);
        if (lane >= off) inc += o;
    }
    if (lane == 63) wtmp[wave] = inc;
    __syncthreads();
    u32 woff = 0;
    #pragma unroll
    for (int w = 0; w < 3; ++w) if (w < wave) woff += wtmp[w];
    u32 excl = woff + inc - run;   // exclusive prefix for this thread's chunk
    #pragma unroll
    for (int k = 0; k < 8; ++k) { u32 x = v[k]; arr[tid * 8 + k] = excl; excl += x; }
    __syncthreads();
}

// Exclusive scan of 2048 f32, src -> dst (src preserved). Ends with __syncthreads.
__device__ __forceinline__ void scan2048_f32(const float* src, float* dst, float* wtmp) {
    const int tid = threadIdx.x, lane = tid & 63, wave = tid >> 6;
    float v[8];
    float run = 0.0f;
    #pragma unroll
    for (int k = 0; k < 8; ++k) { v[k] = src[tid * 8 + k]; run += v[k]; }
    float inc = run;
    #pragma unroll
    for (int off = 1; off < 64; off <<= 1) {
        float o = __shfl_up(inc, off, 64);
        if (lane >= off) inc += o;
    }
    if (lane == 63) wtmp[wave] = inc;
    __syncthreads();
    float woff = 0.0f;
    #pragma unroll
    for (int w = 0; w < 3; ++w) if (w < wave) woff += wtmp[w];
    float excl = woff + inc - run;
    #pragma unroll
    for (int k = 0; k < 8; ++k) { float x = v[k]; dst[tid * 8 + k] = excl; excl += x; }
    __syncthreads();
}

__global__ __launch_bounds__(NTHREADS)
void listmle_kernel(const float* __restrict__ scores,
                    const float* __restrict__ relevance,
                    const float* __restrict__ mask,
                    double* __restrict__ acc) {
    __shared__ u32   startb[NB];     // counts -> exclusive starts (in-place scan)
    __shared__ float relS[N_COLS];   // relevance, bucket-sorted order
    __shared__ float eS[N_COLS];     // exp(s-M), bucket-sorted order
    __shared__ float cex[N_COLS];    // exclusive positional prefix of eS
    __shared__ u32   wtmpu[4];
    __shared__ float wtmpf[4];
    __shared__ float redf[4];

    const int tid = threadIdx.x;
    const size_t base = (size_t)blockIdx.x * N_COLS;

    // ---- load (float4-coalesced) ----
    float sv[EPT], rv[EPT];
    bool  mk[EPT];
    float lmax = -INFINITY;
    #pragma unroll
    for (int c = 0; c < 2; ++c) {
        const int k4 = tid + c * NTHREADS;                 // float4 index
        float4 s4 = ((const float4*)(scores    + base))[k4];
        float4 r4 = ((const float4*)(relevance + base))[k4];
        float4 m4 = ((const float4*)(mask      + base))[k4];
        float ss[4] = {s4.x, s4.y, s4.z, s4.w};
        float rr[4] = {r4.x, r4.y, r4.z, r4.w};
        float mm[4] = {m4.x, m4.y, m4.z, m4.w};
        #pragma unroll
        for (int j = 0; j < 4; ++j) {
            const int e = c * 4 + j;
            mk[e] = (mm[j] != 0.0f);
            sv[e] = ss[j];
            rv[e] = rr[j];
            lmax = fmaxf(lmax, mk[e] ? ss[j] : -INFINITY);
        }
    }

    // zero bucket counters while the max reduction is in flight
    #pragma unroll
    for (int k = 0; k < 8; ++k) startb[tid * 8 + k] = 0u;

    // ---- block max M ----
    #pragma unroll
    for (int off = 32; off > 0; off >>= 1)
        lmax = fmaxf(lmax, __shfl_down(lmax, off, 64));
    if ((tid & 63) == 0) redf[tid >> 6] = lmax;
    __syncthreads();
    const float M = fmaxf(fmaxf(redf[0], redf[1]), fmaxf(redf[2], redf[3]));

    // ---- bucket + histogram (slot = old count) ----
    float ex[EPT];
    int   bk[EPT];
    u32   slot[EPT];
    #pragma unroll
    for (int k = 0; k < EPT; ++k) {
        ex[k] = mk[k] ? __expf(sv[k] - M) : 0.0f;
        int b = (int)(rv[k] * (float)NB);
        b = b < 0 ? 0 : (b > NB - 1 ? NB - 1 : b);
        bk[k] = b;
        slot[k] = atomicAdd(&startb[b], 1u);
    }
    __syncthreads();

    // ---- counts -> exclusive starts ----
    scan2048_u32_inplace(startb, wtmpu);

    // ---- scatter into bucket-sorted order ----
    u32 pos[EPT];
    #pragma unroll
    for (int k = 0; k < EPT; ++k) {
        pos[k] = startb[bk[k]] + slot[k];
        relS[pos[k]] = rv[k];
        eS[pos[k]]   = ex[k];
    }
    __syncthreads();

    // ---- exclusive positional prefix of exp values ----
    scan2048_f32(eS, cex, wtmpf);

    // ---- per-element loss terms ----
    // T_j = sum_{k: rel_k <= rel_j} exp(s_k - M)  (ties broken by scatter position)
    // term = M + log(T_j) - s_j ; summed over all unmasked j (rank N-1 term is 0 identically)
    float lsum = 0.0f;
    #pragma unroll
    for (int k = 0; k < EPT; ++k) {
        if (mk[k]) {
            const int b = bk[k];
            const u32 p0 = startb[b];
            const u32 p1 = (b == NB - 1) ? (u32)N_COLS : startb[b + 1];
            float t = cex[p0];                       // sum over all lower buckets
            const float rj = rv[k];
            for (u32 p = p0; p < p1; ++p) {          // avg 1-2 iterations (Poisson(1))
                const float r = relS[p];
                if (r < rj || (r == rj && p <= pos[k])) t += eS[p];
            }
            lsum += M + __logf(t) - sv[k];
        }
    }

    // ---- block reduce + global accumulate ----
    #pragma unroll
    for (int off = 32; off > 0; off >>= 1)
        lsum += __shfl_down(lsum, off, 64);
    __syncthreads();
    if ((tid & 63) == 0) redf[tid >> 6] = lsum;
    __syncthreads();
    if (tid == 0)
        atomicAdd(acc, (double)(redf[0] + redf[1] + redf[2] + redf[3]));
}

extern "C" void kernel_launch(void* const* d_in, const int* in_sizes, int n_in,
                              void* d_out, int out_size, void* d_ws, size_t ws_size,
                              hipStream_t stream) {
    const float* scores    = (const float*)d_in[0];
    const float* relevance = (const float*)d_in[1];
    const float* mask      = (const float*)d_in[2];
    float* out  = (float*)d_out;
    double* acc = (double*)d_ws;
    const int brows = in_sizes[0] / N_COLS;

    init_acc<<<1, 1, 0, stream>>>(acc);
    listmle_kernel<<<brows, NTHREADS, 0, stream>>>(scores, relevance, mask, acc);
    finalize<<<1, 1, 0, stream>>>(acc, out, brows);
}